// Round 6
// baseline (202.379 us; speedup 1.0000x reference)
//
#include <hip/hip_runtime.h>

// PositionalSparseLinear2d: out[b,o] = sum_k input[b, conn[o,k]] * weights[o,k]
// B=64, N_in = N_out = 512*512 = 262144, K=8, fp32 in/out.
// x_t is stored BF16 (threshold 7.3e-2; measured bf16 absmax 0.0156): row =
// 64*2B = 128 B = one fetch granule.
//
// R10 = R9 + gather block-churn fix:
//  * gather: 4 o-tiles per block (grid 8192 -> 2048 = exactly one residency
//    generation: 8 blocks/CU x 256 CU). Theory: R9's 67% measured occupancy
//    with zero architectural limit (28 VGPR, 0 LDS) = CU drain between
//    short-lived blocks. Unrolled 4-tile loop + __restrict__ lets the
//    compiler overlap next tile's conn/w/x_t loads with current tile's
//    drain; __launch_bounds__(256,8) caps VGPR at 64 so 8 blocks/CU holds.
//  * transpose unchanged (never appears in top-5 -> <54 us; floor ~16 us).
//  * NT input loads kept; NT stores stay dead (R3: WRITE 66->118 MB).

#define IN_N  (512*512)
#define OUT_N (512*512)
#define BATCH 64
#define KCONN 8
#define TIDX  128   // idx-columns per transpose tile
#define OTILES 4    // o-tiles (32 outputs each) per gather block

typedef float f32x4 __attribute__((ext_vector_type(4)));

__device__ inline unsigned f2bf(float f) {                  // RNE fp32->bf16
    unsigned u; __builtin_memcpy(&u, &f, 4);
    return (u + 0x7fffu + ((u >> 16) & 1u)) >> 16;
}
__device__ inline float bflo(unsigned u) {                  // low bf16 -> fp32
    unsigned v = u << 16; float f; __builtin_memcpy(&f, &v, 4); return f;
}
__device__ inline float bfhi(unsigned u) {                  // high bf16 -> fp32
    unsigned v = u & 0xffff0000u; float f; __builtin_memcpy(&f, &v, 4); return f;
}

// ---------------------------------------------------------------------------
// Kernel 1: transpose+downconvert input (BATCH, IN_N) fp32 -> x_t (IN_N,
// BATCH) bf16. 128-idx x 64-batch tile, 256 threads, 2048 blocks (= one
// residency generation). NT float4 loads; bf16 conversion pre-LDS; packed
// pairs; LDS = 64 x 65 uints = 16.6 KB -> 8 blocks/CU. Readout: per wave
// store = 1 KB contiguous; LDS read banks 2-way (free).
// ---------------------------------------------------------------------------
__global__ __launch_bounds__(256, 8) void transpose_kernel(const float* __restrict__ in,
                                                           unsigned short* __restrict__ xt) {
    __shared__ unsigned lds_u[BATCH][TIDX / 2 + 1];   // 64 x 65 x 4 B = 16.6 KB
    const int t    = threadIdx.x;
    const int idx0 = blockIdx.x * TIDX;

    const int lb = t >> 5;          // 0..7
    const int lc = (t & 31) << 2;   // 0,4,...,124
#pragma unroll
    for (int p = 0; p < 8; ++p) {
        const int b = p * 8 + lb;
        f32x4 v = __builtin_nontemporal_load(
            (const f32x4*)(in + (size_t)b * IN_N + idx0 + lc));
        lds_u[b][(lc >> 1) + 0] = f2bf(v.x) | (f2bf(v.y) << 16);
        lds_u[b][(lc >> 1) + 1] = f2bf(v.z) | (f2bf(v.w) << 16);
    }
    __syncthreads();

    const int si = t >> 3;          // 0..31 (uint column within pass)
    const int sb = (t & 7) << 3;    // batch start: 0,8,...,56
#pragma unroll
    for (int p = 0; p < 2; ++p) {
        const int col = p * 32 + si;        // packed column = idx pair {2col, 2col+1}
        unsigned lo[4], hi[4];
#pragma unroll
        for (int j = 0; j < 4; ++j) {
            const unsigned a  = lds_u[sb + 2 * j + 0][col];
            const unsigned b2 = lds_u[sb + 2 * j + 1][col];
            lo[j] = (a & 0xffffu) | (b2 << 16);          // idx 2col,   batches sb+2j, sb+2j+1
            hi[j] = (a >> 16) | (b2 & 0xffff0000u);      // idx 2col+1, batches sb+2j, sb+2j+1
        }
        union { unsigned u[4]; uint4 v; } pk;
        pk.u[0] = lo[0]; pk.u[1] = lo[1]; pk.u[2] = lo[2]; pk.u[3] = lo[3];
        *(uint4*)(xt + (size_t)(idx0 + 2 * col + 0) * BATCH + sb) = pk.v;
        pk.u[0] = hi[0]; pk.u[1] = hi[1]; pk.u[2] = hi[2]; pk.u[3] = hi[3];
        *(uint4*)(xt + (size_t)(idx0 + 2 * col + 1) * BATCH + sb) = pk.v;
    }
}

// ---------------------------------------------------------------------------
// Kernel 2: gather on bf16 x_t. Lane = (o_local = t>>3, chunk = t&7).
// Per k, the 8 lanes of an o-group read ONE x_t row contiguously; all 8
// row-loads prefetched into r[0..7] before first use (R9 win). Each block
// now processes OTILES=4 consecutive o-tiles; iterations are independent
// (__restrict__) so the compiler pipelines tile i+1's loads under tile i.
// ---------------------------------------------------------------------------
__global__ __launch_bounds__(256, 8) void gather_kernel(const unsigned short* __restrict__ xt,
                                                        const int* __restrict__ conn,
                                                        const float* __restrict__ w,
                                                        float* __restrict__ out) {
    const int t  = threadIdx.x;
    const int ol = t >> 3;                   // 0..31
    const int ch = t & 7;                    // batch chunk: batches ch*8..ch*8+7
    const int ob = blockIdx.x * (32 * OTILES) + ol;

#pragma unroll
    for (int i = 0; i < OTILES; ++i) {
        const int o = ob + i * 32;

        // All 8 lanes of a group load the same conn/w rows (same-address merge).
        const int4   c0 = ((const int4*)conn)[(size_t)o * 2 + 0];
        const int4   c1 = ((const int4*)conn)[(size_t)o * 2 + 1];
        const float4 w0 = ((const float4*)w)[(size_t)o * 2 + 0];
        const float4 w1 = ((const float4*)w)[(size_t)o * 2 + 1];
        const int   cidx[KCONN] = {c0.x, c0.y, c0.z, c0.w, c1.x, c1.y, c1.z, c1.w};
        const float wk[KCONN]   = {w0.x, w0.y, w0.z, w0.w, w1.x, w1.y, w1.z, w1.w};

        // Prefetch: 8 independent 16 B loads, all in flight simultaneously.
        uint4 r[KCONN];
#pragma unroll
        for (int k = 0; k < KCONN; ++k) {
            r[k] = *(const uint4*)(xt + (size_t)cidx[k] * BATCH + ch * 8);
        }

        float acc[8] = {0.f, 0.f, 0.f, 0.f, 0.f, 0.f, 0.f, 0.f};
#pragma unroll
        for (int k = 0; k < KCONN; ++k) {
            const unsigned q[4] = {r[k].x, r[k].y, r[k].z, r[k].w};
            const float wv = wk[k];
#pragma unroll
            for (int e = 0; e < 4; ++e) {
                acc[2 * e + 0] += bflo(q[e]) * wv;
                acc[2 * e + 1] += bfhi(q[e]) * wv;
            }
        }

#pragma unroll
        for (int j = 0; j < 8; ++j) {
            out[(size_t)(ch * 8 + j) * OUT_N + o] = acc[j];
        }
    }
}

// ---------------------------------------------------------------------------
// Fallback (only if workspace is too small for the 33.5 MiB bf16 copy).
// ---------------------------------------------------------------------------
__global__ __launch_bounds__(256) void direct_kernel(const float* __restrict__ in,
                                                     const int* __restrict__ conn,
                                                     const float* __restrict__ w,
                                                     float* __restrict__ out) {
    const int o = blockIdx.x * 256 + threadIdx.x;

    const int4   c0 = ((const int4*)conn)[(size_t)o * 2 + 0];
    const int4   c1 = ((const int4*)conn)[(size_t)o * 2 + 1];
    const float4 w0 = ((const float4*)w)[(size_t)o * 2 + 0];
    const float4 w1 = ((const float4*)w)[(size_t)o * 2 + 1];

    const int   cidx[KCONN] = {c0.x, c0.y, c0.z, c0.w, c1.x, c1.y, c1.z, c1.w};
    const float wk[KCONN]   = {w0.x, w0.y, w0.z, w0.w, w1.x, w1.y, w1.z, w1.w};

    for (int b = 0; b < BATCH; ++b) {
        const float* xb = in + (size_t)b * IN_N;
        float acc = 0.0f;
#pragma unroll
        for (int k = 0; k < KCONN; ++k) acc += xb[cidx[k]] * wk[k];
        out[(size_t)b * OUT_N + o] = acc;
    }
}

extern "C" void kernel_launch(void* const* d_in, const int* in_sizes, int n_in,
                              void* d_out, int out_size, void* d_ws, size_t ws_size,
                              hipStream_t stream) {
    const float* inp  = (const float*)d_in[0];   // (64, 512, 512) fp32
    const int*   conn = (const int*)d_in[1];     // (262144, 8) int32
    const float* w    = (const float*)d_in[2];   // (262144, 8) fp32
    float*       out  = (float*)d_out;           // (64, 262144) fp32

    const size_t xt_bytes = (size_t)IN_N * BATCH * sizeof(unsigned short);  // 33.5 MiB

    if (ws_size >= xt_bytes) {
        unsigned short* xt = (unsigned short*)d_ws;
        transpose_kernel<<<IN_N / TIDX, 256, 0, stream>>>(inp, xt);
        gather_kernel<<<OUT_N / (32 * OTILES), 256, 0, stream>>>(xt, conn, w, out);
    } else {
        direct_kernel<<<OUT_N / 256, 256, 0, stream>>>(inp, conn, w, out);
    }
}

// Round 7
// 172.155 us; speedup vs baseline: 1.1756x; 1.1756x over previous
//
#include <hip/hip_runtime.h>

// PositionalSparseLinear2d: out[b,o] = sum_k input[b, conn[o,k]] * weights[o,k]
// B=64, N_in = N_out = 512*512 = 262144, K=8, fp32 in/out.
// x_t is stored BF16 (threshold 7.3e-2; measured bf16 absmax 0.0156): row =
// 64*2B = 128 B = one fetch granule.
//
// R11 = R5/R9 restored (best measured: 170.1 us) + transpose load prefetch.
//  * R6/R10 OTILES=4 REVERTED: FETCH 128->155 MB, WRITE 66->110 MB, occ
//    57% -- long blocks destroy cross-block temporal clustering of the
//    random x_t stream AND separate the 4-wave partial-line out writes in
//    time (partial-line churn). Short blocks, loads clustered at block
//    start, one o-tile per block is the proven shape.
//  * gather: unchanged from R5 (8-load prefetch win, -9 us).
//  * transpose: prefetch all 8 NT float4 loads into registers before the
//    LDS-write loop (same exposed-latency mechanism as the gather win;
//    ~62 VGPR, still 8 blocks/CU).
// Ledger: NT out stores dead (R3, write amp). L2-pollution theory dead
// (R3, FETCH immovable). MLP-per-thread dead (R6). Residual (total-gather)
// constant 115+-1 us across 5 rounds -> transpose ~BW-floor + harness-fixed.

#define IN_N  (512*512)
#define OUT_N (512*512)
#define BATCH 64
#define KCONN 8
#define TIDX  128   // idx-columns per transpose tile

typedef float f32x4 __attribute__((ext_vector_type(4)));

__device__ inline unsigned f2bf(float f) {                  // RNE fp32->bf16
    unsigned u; __builtin_memcpy(&u, &f, 4);
    return (u + 0x7fffu + ((u >> 16) & 1u)) >> 16;
}
__device__ inline float bflo(unsigned u) {                  // low bf16 -> fp32
    unsigned v = u << 16; float f; __builtin_memcpy(&f, &v, 4); return f;
}
__device__ inline float bfhi(unsigned u) {                  // high bf16 -> fp32
    unsigned v = u & 0xffff0000u; float f; __builtin_memcpy(&f, &v, 4); return f;
}

// ---------------------------------------------------------------------------
// Kernel 1: transpose+downconvert input (BATCH, IN_N) fp32 -> x_t (IN_N,
// BATCH) bf16. 128-idx x 64-batch tile, 256 threads, 2048 blocks.
// Load: 8 NT float4 prefetched into registers (all in flight), then convert
// fp32->bf16, pack idx-pairs, 8 B LDS stores (2-way banks, free).
// LDS = 64 x 65 uints = 16.6 KB -> 8 blocks/CU.
// Readout: per wave-instruction stores cover full 128 B rows (no partial
// lines); LDS read banks 2-way (free).
// ---------------------------------------------------------------------------
__global__ __launch_bounds__(256, 8) void transpose_kernel(const float* __restrict__ in,
                                                           unsigned short* __restrict__ xt) {
    __shared__ unsigned lds_u[BATCH][TIDX / 2 + 1];   // 64 x 65 x 4 B = 16.6 KB
    const int t    = threadIdx.x;
    const int idx0 = blockIdx.x * TIDX;

    const int lb = t >> 5;          // 0..7
    const int lc = (t & 31) << 2;   // 0,4,...,124

    // Prefetch: all 8 independent NT loads issued before any LDS write.
    f32x4 v[8];
#pragma unroll
    for (int p = 0; p < 8; ++p) {
        const int b = p * 8 + lb;
        v[p] = __builtin_nontemporal_load(
            (const f32x4*)(in + (size_t)b * IN_N + idx0 + lc));
    }
#pragma unroll
    for (int p = 0; p < 8; ++p) {
        const int b = p * 8 + lb;
        lds_u[b][(lc >> 1) + 0] = f2bf(v[p].x) | (f2bf(v[p].y) << 16);
        lds_u[b][(lc >> 1) + 1] = f2bf(v[p].z) | (f2bf(v[p].w) << 16);
    }
    __syncthreads();

    const int si = t >> 3;          // 0..31 (uint column within pass)
    const int sb = (t & 7) << 3;    // batch start: 0,8,...,56
#pragma unroll
    for (int p = 0; p < 2; ++p) {
        const int col = p * 32 + si;        // packed column = idx pair {2col, 2col+1}
        unsigned lo[4], hi[4];
#pragma unroll
        for (int j = 0; j < 4; ++j) {
            const unsigned a  = lds_u[sb + 2 * j + 0][col];
            const unsigned b2 = lds_u[sb + 2 * j + 1][col];
            lo[j] = (a & 0xffffu) | (b2 << 16);          // idx 2col,   batches sb+2j, sb+2j+1
            hi[j] = (a >> 16) | (b2 & 0xffff0000u);      // idx 2col+1, batches sb+2j, sb+2j+1
        }
        union { unsigned u[4]; uint4 v4; } pk;
        pk.u[0] = lo[0]; pk.u[1] = lo[1]; pk.u[2] = lo[2]; pk.u[3] = lo[3];
        *(uint4*)(xt + (size_t)(idx0 + 2 * col + 0) * BATCH + sb) = pk.v4;
        pk.u[0] = hi[0]; pk.u[1] = hi[1]; pk.u[2] = hi[2]; pk.u[3] = hi[3];
        *(uint4*)(xt + (size_t)(idx0 + 2 * col + 1) * BATCH + sb) = pk.v4;
    }
}

// ---------------------------------------------------------------------------
// Kernel 2: gather on bf16 x_t (R5 shape, proven best). Lane = (o_local =
// t>>3, chunk = t&7). Per k, the 8 lanes of an o-group read ONE x_t row
// contiguously; all 8 row-loads prefetched into r[0..7] before first use
// (one exposed latency instead of eight). One o-tile per block: short-lived
// blocks keep the random stream temporally clustered (R6 lesson).
// ---------------------------------------------------------------------------
__global__ __launch_bounds__(256, 8) void gather_kernel(const unsigned short* __restrict__ xt,
                                                        const int* __restrict__ conn,
                                                        const float* __restrict__ w,
                                                        float* __restrict__ out) {
    const int t  = threadIdx.x;
    const int o0 = blockIdx.x * 32;          // 32 outputs per block
    const int ol = t >> 3;                   // 0..31
    const int ch = t & 7;                    // batch chunk: batches ch*8..ch*8+7
    const int o  = o0 + ol;

    // All 8 lanes of a group load the same conn/w rows (same-address merge).
    const int4   c0 = ((const int4*)conn)[(size_t)o * 2 + 0];
    const int4   c1 = ((const int4*)conn)[(size_t)o * 2 + 1];
    const float4 w0 = ((const float4*)w)[(size_t)o * 2 + 0];
    const float4 w1 = ((const float4*)w)[(size_t)o * 2 + 1];
    const int   cidx[KCONN] = {c0.x, c0.y, c0.z, c0.w, c1.x, c1.y, c1.z, c1.w};
    const float wk[KCONN]   = {w0.x, w0.y, w0.z, w0.w, w1.x, w1.y, w1.z, w1.w};

    // Prefetch: 8 independent 16 B loads, all in flight simultaneously.
    uint4 r[KCONN];
#pragma unroll
    for (int k = 0; k < KCONN; ++k) {
        r[k] = *(const uint4*)(xt + (size_t)cidx[k] * BATCH + ch * 8);
    }

    float acc[8] = {0.f, 0.f, 0.f, 0.f, 0.f, 0.f, 0.f, 0.f};
#pragma unroll
    for (int k = 0; k < KCONN; ++k) {
        const unsigned q[4] = {r[k].x, r[k].y, r[k].z, r[k].w};
        const float wv = wk[k];
#pragma unroll
        for (int e = 0; e < 4; ++e) {
            acc[2 * e + 0] += bflo(q[e]) * wv;
            acc[2 * e + 1] += bfhi(q[e]) * wv;
        }
    }

#pragma unroll
    for (int j = 0; j < 8; ++j) {
        out[(size_t)(ch * 8 + j) * OUT_N + o] = acc[j];
    }
}

// ---------------------------------------------------------------------------
// Fallback (only if workspace is too small for the 33.5 MiB bf16 copy).
// ---------------------------------------------------------------------------
__global__ __launch_bounds__(256) void direct_kernel(const float* __restrict__ in,
                                                     const int* __restrict__ conn,
                                                     const float* __restrict__ w,
                                                     float* __restrict__ out) {
    const int o = blockIdx.x * 256 + threadIdx.x;

    const int4   c0 = ((const int4*)conn)[(size_t)o * 2 + 0];
    const int4   c1 = ((const int4*)conn)[(size_t)o * 2 + 1];
    const float4 w0 = ((const float4*)w)[(size_t)o * 2 + 0];
    const float4 w1 = ((const float4*)w)[(size_t)o * 2 + 1];

    const int   cidx[KCONN] = {c0.x, c0.y, c0.z, c0.w, c1.x, c1.y, c1.z, c1.w};
    const float wk[KCONN]   = {w0.x, w0.y, w0.z, w0.w, w1.x, w1.y, w1.z, w1.w};

    for (int b = 0; b < BATCH; ++b) {
        const float* xb = in + (size_t)b * IN_N;
        float acc = 0.0f;
#pragma unroll
        for (int k = 0; k < KCONN; ++k) acc += xb[cidx[k]] * wk[k];
        out[(size_t)b * OUT_N + o] = acc;
    }
}

extern "C" void kernel_launch(void* const* d_in, const int* in_sizes, int n_in,
                              void* d_out, int out_size, void* d_ws, size_t ws_size,
                              hipStream_t stream) {
    const float* inp  = (const float*)d_in[0];   // (64, 512, 512) fp32
    const int*   conn = (const int*)d_in[1];     // (262144, 8) int32
    const float* w    = (const float*)d_in[2];   // (262144, 8) fp32
    float*       out  = (float*)d_out;           // (64, 262144) fp32

    const size_t xt_bytes = (size_t)IN_N * BATCH * sizeof(unsigned short);  // 33.5 MiB

    if (ws_size >= xt_bytes) {
        unsigned short* xt = (unsigned short*)d_ws;
        transpose_kernel<<<IN_N / TIDX, 256, 0, stream>>>(inp, xt);
        gather_kernel<<<OUT_N / 32, 256, 0, stream>>>(xt, conn, w, out);
    } else {
        direct_kernel<<<OUT_N / 256, 256, 0, stream>>>(inp, conn, w, out);
    }
}